// Round 8
// baseline (481.139 us; speedup 1.0000x reference)
//
#include <hip/hip_runtime.h>
#include <cstdint>
#include <cstddef>

// ---------------------------------------------------------------------------
// GraphSAGE (4x SAGEConv + ReLU + log_softmax) on MI355X — round 8.
//   - Atomic-free edge sort (r5-r7, proven): bucket_pass1 -> colsum (4 blk)
//     -> scan -> bucket_gather (LDS entry cache).
//   - NEW: per-node neighbor lists sorted by src id (wave bitonic via
//     __shfl_xor) -> all waves sweep the feature table in the same
//     direction -> gather working set becomes a narrow moving window ->
//     L2-resident -> fewer L3-serviced misses in all 4 agg passes.
//   - Mean aggregation: per-node register accumulate, 4-deep pipelined.
//   - bf16 MFMA GEMM: BM=256 BN=128 BK=64, 512 thr / 8 waves.
//   - transform-first layers 3/4; prep_all now also converts x -> bf16.
// ---------------------------------------------------------------------------

typedef short s16x8 __attribute__((ext_vector_type(8)));
typedef float f32x4 __attribute__((ext_vector_type(4)));
typedef unsigned short u16;
typedef unsigned short u16x8 __attribute__((ext_vector_type(8)));

#define EPB 8192   // edges per pass-1 block
#define EPT 32     // edges per thread in pass-1 (EPB/256)
#define GCAP 6144  // bucket_gather LDS entry cache

__device__ __forceinline__ float b2f(u16 u) {
    union { unsigned int i; float f; } x; x.i = ((unsigned int)u) << 16; return x.f;
}
__device__ __forceinline__ u16 f2b(float f) {
    union { float f; unsigned int i; } x; x.f = f;
    unsigned int r = x.i + 0x7FFFu + ((x.i >> 16) & 1u);  // RNE
    return (u16)(r >> 16);
}

// ---------------- CSR build, pass 1: per-block counting sort by bucket ------

__global__ __launch_bounds__(256) void bucket_pass1(
    const int* __restrict__ src, const int* __restrict__ dst, int E,
    unsigned* __restrict__ gOffs, unsigned* __restrict__ staged, int nbkt)
{
    __shared__ unsigned offs[1025];
    __shared__ unsigned tsum[256];
    const int tid = threadIdx.x;
    const int e0 = blockIdx.x * EPB;

    for (int i = tid; i < nbkt; i += 256) offs[i] = 0u;
    __syncthreads();

    for (int t = 0; t < EPT; ++t) {
        int e = e0 + t * 256 + tid;
        if (e < E) atomicAdd(&offs[((unsigned)dst[e]) >> 7], 1u);  // int LDS atomic
    }
    __syncthreads();

    unsigned c[4], sum = 0;
#pragma unroll
    for (int i = 0; i < 4; ++i) {
        int idx = tid * 4 + i;
        c[i] = sum;
        sum += (idx < nbkt) ? offs[idx] : 0u;
    }
    tsum[tid] = sum;
    __syncthreads();
    for (int off = 1; off < 256; off <<= 1) {
        unsigned v = (tid >= off) ? tsum[tid - off] : 0u;
        __syncthreads();
        tsum[tid] += v;
        __syncthreads();
    }
    unsigned base = (tid == 0) ? 0u : tsum[tid - 1];
    unsigned total = tsum[255];
#pragma unroll
    for (int i = 0; i < 4; ++i) {
        int idx = tid * 4 + i;
        if (idx < nbkt) offs[idx] = base + c[i];
    }
    if (tid == 0) offs[nbkt] = total;
    __syncthreads();

    for (int i = tid; i <= nbkt; i += 256)
        gOffs[(size_t)blockIdx.x * (nbkt + 1) + i] = offs[i];
    __syncthreads();

    for (int t = 0; t < EPT; ++t) {
        int e = e0 + t * 256 + tid;
        if (e < E) {
            unsigned d = (unsigned)dst[e];
            unsigned s = (unsigned)src[e];
            unsigned p = atomicAdd(&offs[d >> 7], 1u);
            staged[(size_t)e0 + p] = (s << 7) | (d & 127u);
        }
    }
}

// ---------------- CSR pass 2a: per-bucket totals (multi-block, coalesced) ---

__global__ void colsum_kernel(const unsigned* __restrict__ gOffs, int nblk, int nbkt,
                              unsigned* __restrict__ bktCnt) {
    int b = blockIdx.x * 256 + threadIdx.x;
    if (b >= nbkt) return;
    unsigned s = 0;
    for (int blk = 0; blk < nblk; ++blk) {
        const unsigned* row = gOffs + (size_t)blk * (nbkt + 1);
        s += row[b + 1] - row[b];
    }
    bktCnt[b] = s;
}

// ---------------- CSR pass 2b: exclusive scan of bucket totals --------------

__global__ __launch_bounds__(1024) void scan_base(
    const unsigned* __restrict__ bktCnt, int nbkt, unsigned* __restrict__ bktBase)
{
    __shared__ unsigned lds[1024];
    int t = threadIdx.x;
    unsigned v = (t < nbkt) ? bktCnt[t] : 0u;
    lds[t] = v;
    __syncthreads();
    for (int off = 1; off < 1024; off <<= 1) {
        unsigned u = (t >= off) ? lds[t - off] : 0u;
        __syncthreads();
        lds[t] += u;
        __syncthreads();
    }
    if (t <= nbkt) bktBase[t] = lds[t] - v;
}

// ---------------- CSR pass 3: per-bucket node sort -> ssrc + rp -------------

__global__ __launch_bounds__(256) void bucket_gather(
    const unsigned* __restrict__ gOffs, const unsigned* __restrict__ staged,
    const unsigned* __restrict__ bktBase, int nblk, int nbkt, int Nn, int E,
    int* __restrict__ ssrc, int* __restrict__ rp)
{
    __shared__ unsigned segS[256];
    __shared__ unsigned segBase[257];
    __shared__ unsigned tsum[256];
    __shared__ unsigned nodeCnt[128];
    __shared__ unsigned cursor[128];
    __shared__ unsigned ents[GCAP];
    const int tid = threadIdx.x;
    const int bkt = blockIdx.x;
    const int stride = nbkt + 1;

    unsigned len = 0;
    if (tid < nblk) {
        unsigned s = gOffs[(size_t)tid * stride + bkt];
        unsigned e = gOffs[(size_t)tid * stride + bkt + 1];
        segS[tid] = s;
        len = e - s;
    }
    tsum[tid] = len;
    __syncthreads();
    for (int off = 1; off < 256; off <<= 1) {
        unsigned u = (tid >= off) ? tsum[tid - off] : 0u;
        __syncthreads();
        tsum[tid] += u;
        __syncthreads();
    }
    segBase[tid] = tsum[tid] - len;
    if (tid == 255) segBase[256] = tsum[255];
    if (tid < 128) nodeCnt[tid] = 0u;
    __syncthreads();

    const unsigned total = segBase[nblk];
    const bool cached = (total <= (unsigned)GCAP);

    // pass A: per-node counts (+ cache entries)
    for (unsigned p = tid; p < total; p += 256) {
        int lo = 0, hi = nblk;
        while (hi - lo > 1) {
            int mid = (lo + hi) >> 1;
            if (segBase[mid] <= p) lo = mid; else hi = mid;
        }
        unsigned ent = staged[(size_t)lo * EPB + segS[lo] + (p - segBase[lo])];
        if (cached) ents[p] = ent;
        atomicAdd(&nodeCnt[ent & 127u], 1u);
    }
    __syncthreads();

    unsigned nc = (tid < 128) ? nodeCnt[tid] : 0u;
    tsum[tid] = nc;
    __syncthreads();
    for (int off = 1; off < 128; off <<= 1) {
        unsigned u = (tid >= off) ? tsum[tid - off] : 0u;
        __syncthreads();
        tsum[tid] += u;
        __syncthreads();
    }
    if (tid < 128) {
        unsigned off0 = tsum[tid] - nc;
        cursor[tid] = off0;
        int node = bkt * 128 + tid;
        if (node < Nn) rp[node] = (int)(bktBase[bkt] + off0);
    }
    if (bkt == 0 && tid == 0) rp[Nn] = E;
    __syncthreads();

    // pass B: place entries
    const unsigned gbase = bktBase[bkt];
    for (unsigned p = tid; p < total; p += 256) {
        unsigned ent;
        if (cached) {
            ent = ents[p];
        } else {
            int lo = 0, hi = nblk;
            while (hi - lo > 1) {
                int mid = (lo + hi) >> 1;
                if (segBase[mid] <= p) lo = mid; else hi = mid;
            }
            ent = staged[(size_t)lo * EPB + segS[lo] + (p - segBase[lo])];
        }
        unsigned pos = atomicAdd(&cursor[ent & 127u], 1u);
        ssrc[gbase + pos] = (int)(ent >> 7);
    }
}

// ---------------- NEW: per-node src-sort (wave bitonic, locality only) ------
// One wave per node; deg<=64 sorted ascending via __shfl_xor bitonic network.
// deg>64 left unsorted (P~0 for this graph); correctness is order-independent.

__global__ __launch_bounds__(256) void sort_kernel(
    const int* __restrict__ rp, int* __restrict__ ssrc, int Nn)
{
    int lane = threadIdx.x & 63;
    int n = blockIdx.x * 4 + (threadIdx.x >> 6);
    if (n >= Nn) return;
    int s = rp[n], e = rp[n + 1];
    int deg = e - s;
    if (deg <= 1 || deg > 64) return;          // wave-uniform branch
    int v = (lane < deg) ? ssrc[s + lane] : 0x7FFFFFFF;
#pragma unroll
    for (int k = 2; k <= 64; k <<= 1) {
#pragma unroll
        for (int j = k >> 1; j > 0; j >>= 1) {
            int other = __shfl_xor(v, j);
            bool keepMin = ((lane & j) == 0) == ((lane & k) == 0);
            v = keepMin ? (v < other ? v : other) : (v > other ? v : other);
        }
    }
    if (lane < deg) ssrc[s + lane] = v;
}

// ---------------- prep: x->bf16 + all weights/biases (one kernel) ----------

__device__ __forceinline__ void wtr(const float* W, int K, int Nout, u16* Wt,
                                    int rowOff, int idx) {
    int k = idx / Nout, n = idx - k * Nout;
    Wt[(size_t)(n + rowOff) * K + k] = f2b(W[idx]);
}

__global__ void prep_all(
    const float* __restrict__ x, u16* __restrict__ xb, long xchunks,
    const float* __restrict__ Wl1, const float* __restrict__ Wr1,
    const float* __restrict__ Wl2, const float* __restrict__ Wr2,
    const float* __restrict__ Wl3, const float* __restrict__ Wr3,
    const float* __restrict__ Wl4, const float* __restrict__ Wr4,
    const float* __restrict__ b3, const float* __restrict__ b4,
    u16* __restrict__ W1lt, u16* __restrict__ W1rt,
    u16* __restrict__ W2lt, u16* __restrict__ W2rt,
    u16* __restrict__ W3t,  u16* __restrict__ W4t,
    float* __restrict__ b3c, float* __restrict__ b4c)
{
    long gidx = (long)blockIdx.x * 256 + threadIdx.x;
    if (gidx < xchunks) {                       // x -> bf16, 8 elems/thread
        long i = gidx * 8;
        float4 a = *(const float4*)(x + i);
        float4 b = *(const float4*)(x + i + 4);
        u16x8 v;
        v[0] = f2b(a.x); v[1] = f2b(a.y); v[2] = f2b(a.z); v[3] = f2b(a.w);
        v[4] = f2b(b.x); v[5] = f2b(b.y); v[6] = f2b(b.z); v[7] = f2b(b.w);
        *(u16x8*)(xb + i) = v;
        return;
    }
    int idx = (int)(gidx - xchunks);
    if (idx < 32768) { wtr(Wl1, 128, 256, W1lt, 0, idx); return; }
    idx -= 32768;
    if (idx < 32768) { wtr(Wr1, 128, 256, W1rt, 0, idx); return; }
    idx -= 32768;
    if (idx < 65536) { wtr(Wl2, 256, 256, W2lt, 0, idx); return; }
    idx -= 65536;
    if (idx < 65536) { wtr(Wr2, 256, 256, W2rt, 0, idx); return; }
    idx -= 65536;
    if (idx < 16384) { wtr(Wl3, 256, 64, W3t, 0, idx); return; }
    idx -= 16384;
    if (idx < 16384) { wtr(Wr3, 256, 64, W3t, 64, idx); return; }
    idx -= 16384;
    if (idx < 4096)  { wtr(Wl4, 64, 64, W4t, 0, idx); return; }
    idx -= 4096;
    if (idx < 4096)  { wtr(Wr4, 64, 64, W4t, 64, idx); return; }
    idx -= 4096;
    if (idx < 128)   { b3c[idx] = (idx < 64) ? 0.f : b3[idx - 64]; return; }
    idx -= 128;
    if (idx < 128)   { b4c[idx] = (idx < 64) ? 0.f : b4[idx - 64]; return; }
}

// ---------------- mean aggregation: 4-deep pipelined gather -----------------

template <int LPN, bool ADD, bool RELU, bool LSM>
__global__ __launch_bounds__(256) void agg_kernel(
    const u16* __restrict__ feat, int ldF, int offF,
    const u16* __restrict__ addB, int ldA, int offA,
    void* __restrict__ outp, int ldO,
    const int* __restrict__ rp, const int* __restrict__ ssrc, int Nn)
{
    constexpr int NPW = 64 / LPN;
    int lane = threadIdx.x & 63;
    int wid  = threadIdx.x >> 6;
    int sub  = lane / LPN;
    int sl   = lane % LPN;
    int n = (blockIdx.x * 4 + wid) * NPW + sub;
    if (n >= Nn) return;

    int s = rp[n], e = rp[n + 1];
    float acc[8] = {0.f, 0.f, 0.f, 0.f, 0.f, 0.f, 0.f, 0.f};
    const u16* fbase = feat + (size_t)offF + (size_t)sl * 8;

    for (int k = s; k < e; k += 4) {
        int last = e - 1;
        int k1 = k + 1 <= last ? k + 1 : last;
        int k2 = k + 2 <= last ? k + 2 : last;
        int k3 = k + 3 <= last ? k + 3 : last;
        int sc0 = ssrc[k], sc1 = ssrc[k1], sc2 = ssrc[k2], sc3 = ssrc[k3];
        u16x8 v0 = *(const u16x8*)(fbase + (size_t)sc0 * ldF);
        u16x8 v1 = *(const u16x8*)(fbase + (size_t)sc1 * ldF);
        u16x8 v2 = *(const u16x8*)(fbase + (size_t)sc2 * ldF);
        u16x8 v3 = *(const u16x8*)(fbase + (size_t)sc3 * ldF);
#pragma unroll
        for (int j = 0; j < 8; ++j) acc[j] += b2f(v0[j]);
        if (k + 1 < e) {
#pragma unroll
            for (int j = 0; j < 8; ++j) acc[j] += b2f(v1[j]);
        }
        if (k + 2 < e) {
#pragma unroll
            for (int j = 0; j < 8; ++j) acc[j] += b2f(v2[j]);
        }
        if (k + 3 < e) {
#pragma unroll
            for (int j = 0; j < 8; ++j) acc[j] += b2f(v3[j]);
        }
    }

    int cnt = e - s;
    float inv = 1.0f / (float)(cnt > 0 ? cnt : 1);
#pragma unroll
    for (int j = 0; j < 8; ++j) acc[j] *= inv;

    if constexpr (ADD) {
        u16x8 v = *(const u16x8*)(addB + (size_t)n * ldA + offA + (size_t)sl * 8);
#pragma unroll
        for (int j = 0; j < 8; ++j) acc[j] += b2f(v[j]);
    }
    if constexpr (RELU) {
#pragma unroll
        for (int j = 0; j < 8; ++j) acc[j] = fmaxf(acc[j], 0.f);
    }

    if constexpr (LSM) {
        float m = acc[0];
#pragma unroll
        for (int j = 1; j < 8; ++j) m = fmaxf(m, acc[j]);
#pragma unroll
        for (int off = 1; off < 8; off <<= 1) m = fmaxf(m, __shfl_xor(m, off));
        float ss = 0.f;
#pragma unroll
        for (int j = 0; j < 8; ++j) ss += expf(acc[j] - m);
#pragma unroll
        for (int off = 1; off < 8; off <<= 1) ss += __shfl_xor(ss, off);
        float lse = m + logf(ss);
        float* o = (float*)outp + (size_t)n * ldO + (size_t)sl * 8;
        *(float4*)o = make_float4(acc[0] - lse, acc[1] - lse, acc[2] - lse, acc[3] - lse);
        *(float4*)(o + 4) = make_float4(acc[4] - lse, acc[5] - lse, acc[6] - lse, acc[7] - lse);
    } else {
        u16x8 v;
#pragma unroll
        for (int j = 0; j < 8; ++j) v[j] = f2b(acc[j]);
        *(u16x8*)((u16*)outp + (size_t)n * ldO + (size_t)sl * 8) = v;
    }
}

// ---------------- bf16 MFMA GEMM: BM=256 BN=128 BK=64, 512 thr --------------

template <bool DUAL, bool RELU>
__global__ __launch_bounds__(512, 4) void gemm_mfma(
    const u16* __restrict__ A1, const u16* __restrict__ Wt1, int K1,
    const u16* __restrict__ A2, const u16* __restrict__ Wt2, int K2,
    const float* __restrict__ bias,
    u16* __restrict__ outp, int ldOut, int M)
{
    __shared__ u16 sA[256][72];   // [row][k], pad 64->72 (2-way bank alias = free)
    __shared__ u16 sW[128][72];   // [outcol][k]

    const int tid = threadIdx.x;
    const int lane = tid & 63, wid = tid >> 6;
    const int wr = wid >> 1, wc = wid & 1;          // 4x2 wave grid
    const int r16 = lane & 15, khalf = lane >> 4;   // khalf 0..3
    const int row0 = blockIdx.x * 256;
    const int nB   = blockIdx.y * 128;

    f32x4 acc[4][4] = {};

#pragma unroll 1
    for (int s = 0; s < (DUAL ? 2 : 1); ++s) {
        const u16* A  = (s == 0) ? A1 : A2;
        const u16* Wt = (s == 0) ? Wt1 : Wt2;
        const int  K  = (s == 0) ? K1 : K2;
        for (int k0 = 0; k0 < K; k0 += 64) {
#pragma unroll
            for (int it = 0; it < 4; ++it) {
                int idx = it * 512 + tid;
                int r = idx >> 3, kq = (idx & 7) * 8;
                int grow = row0 + r;
                s16x8 v = {};
                if (grow < M) v = *(const s16x8*)(A + (size_t)grow * K + k0 + kq);
                *(s16x8*)&sA[r][kq] = v;
            }
#pragma unroll
            for (int it = 0; it < 2; ++it) {
                int idx = it * 512 + tid;
                int r = idx >> 3, kq = (idx & 7) * 8;
                s16x8 v = *(const s16x8*)(Wt + (size_t)(nB + r) * K + k0 + kq);
                *(s16x8*)&sW[r][kq] = v;
            }
            __syncthreads();

#pragma unroll
            for (int ks = 0; ks < 2; ++ks) {
                const int kb = ks * 32 + khalf * 8;
                s16x8 af[4], bfr[4];
#pragma unroll
                for (int m = 0; m < 4; ++m)
                    af[m] = *(const s16x8*)&sA[wr * 64 + m * 16 + r16][kb];
#pragma unroll
                for (int nn = 0; nn < 4; ++nn)
                    bfr[nn] = *(const s16x8*)&sW[wc * 64 + nn * 16 + r16][kb];
#pragma unroll
                for (int m = 0; m < 4; ++m)
#pragma unroll
                    for (int nn = 0; nn < 4; ++nn)
                        acc[m][nn] = __builtin_amdgcn_mfma_f32_16x16x32_bf16(
                            af[m], bfr[nn], acc[m][nn], 0, 0, 0);
            }
            __syncthreads();
        }
    }

    // epilogue: C/D layout col=lane&15, row=(lane>>4)*4+reg  [m89]
    float bv[4];
#pragma unroll
    for (int nn = 0; nn < 4; ++nn)
        bv[nn] = bias ? bias[nB + wc * 64 + nn * 16 + r16] : 0.f;
#pragma unroll
    for (int m = 0; m < 4; ++m) {
#pragma unroll
        for (int r = 0; r < 4; ++r) {
            int grow = row0 + wr * 64 + m * 16 + khalf * 4 + r;
            if (grow < M) {
#pragma unroll
                for (int nn = 0; nn < 4; ++nn) {
                    float v = acc[m][nn][r] + bv[nn];
                    if constexpr (RELU) v = fmaxf(v, 0.f);
                    outp[(size_t)grow * ldOut + nB + wc * 64 + nn * 16 + r16] = f2b(v);
                }
            }
        }
    }
}

// ---------------- launch ----------------

extern "C" void kernel_launch(void* const* d_in, const int* in_sizes, int n_in,
                              void* d_out, int out_size, void* d_ws, size_t ws_size,
                              hipStream_t stream)
{
    const float* x   = (const float*)d_in[0];
    const int*   ei  = (const int*)d_in[1];
    const float* Wl1 = (const float*)d_in[2];
    const float* Wr1 = (const float*)d_in[3];
    const float* b1  = (const float*)d_in[4];
    const float* Wl2 = (const float*)d_in[5];
    const float* Wr2 = (const float*)d_in[6];
    const float* b2  = (const float*)d_in[7];
    const float* Wl3 = (const float*)d_in[8];
    const float* Wr3 = (const float*)d_in[9];
    const float* b3  = (const float*)d_in[10];
    const float* Wl4 = (const float*)d_in[11];
    const float* Wr4 = (const float*)d_in[12];
    const float* b4  = (const float*)d_in[13];
    float* outp = (float*)d_out;

    const int N = in_sizes[0] / 128;
    const int E = in_sizes[1] / 2;
    const int* src = ei;
    const int* dst = ei + E;

    const int nbkt = (N + 127) >> 7;          // 128-node buckets
    const int nblk = (E + EPB - 1) / EPB;     // pass-1 blocks (must be <=256)

    char* w = (char*)d_ws;
    auto alloc = [&](size_t bytes) -> char* {
        char* p = w;
        w += (bytes + 255) & ~(size_t)255;
        return p;
    };
    int* ssrc = (int*)alloc((size_t)E * 4);
    int* rp   = (int*)alloc((size_t)(N + 1) * 4);
    unsigned* bktCnt  = (unsigned*)alloc((size_t)nbkt * 4);
    unsigned* bktBase = (unsigned*)alloc((size_t)(nbkt + 1) * 4);
    u16* mean1 = (u16*)alloc((size_t)N * 128 * 2);   // reused as t3r3 [N,128]
    u16* h1    = (u16*)alloc((size_t)N * 256 * 2);   // reused: h3 [N,64] + t4r4 [N,128]
    u16* agg2  = (u16*)alloc((size_t)N * 256 * 2);
    u16* h2s   = (u16*)alloc((size_t)N * 256 * 2);   // h2; start doubles as xb AND
                                                     // (earlier) staged+gOffs scratch
    u16* W1lt = (u16*)alloc((size_t)256 * 128 * 2);
    u16* W1rt = (u16*)alloc((size_t)256 * 128 * 2);
    u16* W2lt = (u16*)alloc((size_t)256 * 256 * 2);
    u16* W2rt = (u16*)alloc((size_t)256 * 256 * 2);
    u16* W3t  = (u16*)alloc((size_t)128 * 256 * 2);
    u16* W4t  = (u16*)alloc((size_t)128 * 64 * 2);
    float* b3c = (float*)alloc(128 * 4);
    float* b4c = (float*)alloc(128 * 4);

    // staged + gOffs overlay the h2s slab; dead before prep_all writes xb.
    unsigned* staged = (unsigned*)h2s;
    unsigned* gOffs  = staged + (size_t)nblk * EPB;

    u16* xb   = h2s;                       // [N,128]; written after CSR done
    u16* h2   = h2s;                       // [N,256]
    u16* t3r3 = mean1;                     // [N,128]
    u16* h3   = h1;                        // [N,64]
    u16* t4r4 = h1 + (size_t)N * 64;       // [N,128]

    dim3 blk(256);
    dim3 blkG(512);
    const int gx = (N + 255) / 256;        // GEMM row-blocks (BM=256)

    // ---- CSR build: atomic-free two-level sort ----
    bucket_pass1<<<nblk, blk, 0, stream>>>(src, dst, E, gOffs, staged, nbkt);
    colsum_kernel<<<(nbkt + 255) / 256, blk, 0, stream>>>(gOffs, nblk, nbkt, bktCnt);
    scan_base<<<1, 1024, 0, stream>>>(bktCnt, nbkt, bktBase);
    bucket_gather<<<nbkt, blk, 0, stream>>>(gOffs, staged, bktBase, nblk, nbkt, N, E,
                                            ssrc, rp);
    // per-node src-sort for gather locality (order-independent math)
    sort_kernel<<<(N + 3) / 4, blk, 0, stream>>>(rp, ssrc, N);

    // ---- prep (x conversion overwrites staged region — CSR reads done) ----
    long xchunks = (long)N * 128 / 8;
    long ptot = xchunks + 237824;
    prep_all<<<(int)((ptot + 255) / 256), blk, 0, stream>>>(
        x, xb, xchunks,
        Wl1, Wr1, Wl2, Wr2, Wl3, Wr3, Wl4, Wr4, b3, b4,
        W1lt, W1rt, W2lt, W2rt, W3t, W4t, b3c, b4c);

    // ---- layer 1: h1 = relu(mean(xb)@Wl1 + xb@Wr1 + b1) ----
    agg_kernel<16, false, false, false><<<(N + 15) / 16, blk, 0, stream>>>(
        xb, 128, 0, nullptr, 0, 0, mean1, 128, rp, ssrc, N);
    gemm_mfma<true, true><<<dim3(gx, 2), blkG, 0, stream>>>(
        mean1, W1lt, 128, xb, W1rt, 128, b1, h1, 256, N);

    // ---- layer 2: h2 = relu(mean(h1)@Wl2 + h1@Wr2 + b2) ----
    agg_kernel<32, false, false, false><<<(N + 7) / 8, blk, 0, stream>>>(
        h1, 256, 0, nullptr, 0, 0, agg2, 256, rp, ssrc, N);
    gemm_mfma<true, true><<<dim3(gx, 2), blkG, 0, stream>>>(
        agg2, W2lt, 256, h1, W2rt, 256, b2, h2, 256, N);

    // ---- layer 3 (transform-first): [t3|r3] = h2@[Wl3|Wr3] + [0|b3] ----
    gemm_mfma<false, false><<<dim3(gx, 1), blkG, 0, stream>>>(
        h2, W3t, 256, nullptr, nullptr, 0, b3c, t3r3, 128, N);
    // h3 = relu(mean(t3) + r3)
    agg_kernel<8, true, true, false><<<(N + 31) / 32, blk, 0, stream>>>(
        t3r3, 128, 0, t3r3, 128, 64, h3, 64, rp, ssrc, N);

    // ---- layer 4 (transform-first): [t4|r4] = h3@[Wl4|Wr4] + [0|b4] ----
    gemm_mfma<false, false><<<dim3(gx, 1), blkG, 0, stream>>>(
        h3, W4t, 64, nullptr, nullptr, 0, b4c, t4r4, 128, N);
    // out = log_softmax(mean(t4) + r4)
    agg_kernel<8, true, false, true><<<(N + 31) / 32, blk, 0, stream>>>(
        t4r4, 128, 0, t4r4, 128, 64, outp, 64, rp, ssrc, N);
}

// Round 9
// 449.673 us; speedup vs baseline: 1.0700x; 1.0700x over previous
//
#include <hip/hip_runtime.h>
#include <cstdint>
#include <cstddef>

// ---------------------------------------------------------------------------
// GraphSAGE (4x SAGEConv + ReLU + log_softmax) on MI355X — round 9.
//   - Atomic-free edge sort (r5-r7, proven): bucket_pass1 -> colsum -> scan
//     -> bucket_gather (LDS entry cache).  [r8's src-sort REVERTED: no effect]
//   - Mean aggregation: per-node register accumulate, 8-deep pipelined gather.
//   - bf16 MFMA GEMM: BM=256 BN=128 BK=64, 512 thr / 8 waves; dual GEMMs use
//     an XCD-aware 1-D grid remap so the two col-block twins sharing A-rows
//     land on the SAME XCD 8 ids apart -> twin's A reads hit that XCD's L2.
//   - transform-first layers 3/4; prep_all converts x + all weights.
// ---------------------------------------------------------------------------

typedef short s16x8 __attribute__((ext_vector_type(8)));
typedef float f32x4 __attribute__((ext_vector_type(4)));
typedef unsigned short u16;
typedef unsigned short u16x8 __attribute__((ext_vector_type(8)));

#define EPB 8192   // edges per pass-1 block
#define EPT 32     // edges per thread in pass-1 (EPB/256)
#define GCAP 6144  // bucket_gather LDS entry cache

__device__ __forceinline__ float b2f(u16 u) {
    union { unsigned int i; float f; } x; x.i = ((unsigned int)u) << 16; return x.f;
}
__device__ __forceinline__ u16 f2b(float f) {
    union { float f; unsigned int i; } x; x.f = f;
    unsigned int r = x.i + 0x7FFFu + ((x.i >> 16) & 1u);  // RNE
    return (u16)(r >> 16);
}

// ---------------- CSR build, pass 1: per-block counting sort by bucket ------

__global__ __launch_bounds__(256) void bucket_pass1(
    const int* __restrict__ src, const int* __restrict__ dst, int E,
    unsigned* __restrict__ gOffs, unsigned* __restrict__ staged, int nbkt)
{
    __shared__ unsigned offs[1025];
    __shared__ unsigned tsum[256];
    const int tid = threadIdx.x;
    const int e0 = blockIdx.x * EPB;

    for (int i = tid; i < nbkt; i += 256) offs[i] = 0u;
    __syncthreads();

    for (int t = 0; t < EPT; ++t) {
        int e = e0 + t * 256 + tid;
        if (e < E) atomicAdd(&offs[((unsigned)dst[e]) >> 7], 1u);  // int LDS atomic
    }
    __syncthreads();

    unsigned c[4], sum = 0;
#pragma unroll
    for (int i = 0; i < 4; ++i) {
        int idx = tid * 4 + i;
        c[i] = sum;
        sum += (idx < nbkt) ? offs[idx] : 0u;
    }
    tsum[tid] = sum;
    __syncthreads();
    for (int off = 1; off < 256; off <<= 1) {
        unsigned v = (tid >= off) ? tsum[tid - off] : 0u;
        __syncthreads();
        tsum[tid] += v;
        __syncthreads();
    }
    unsigned base = (tid == 0) ? 0u : tsum[tid - 1];
    unsigned total = tsum[255];
#pragma unroll
    for (int i = 0; i < 4; ++i) {
        int idx = tid * 4 + i;
        if (idx < nbkt) offs[idx] = base + c[i];
    }
    if (tid == 0) offs[nbkt] = total;
    __syncthreads();

    for (int i = tid; i <= nbkt; i += 256)
        gOffs[(size_t)blockIdx.x * (nbkt + 1) + i] = offs[i];
    __syncthreads();

    for (int t = 0; t < EPT; ++t) {
        int e = e0 + t * 256 + tid;
        if (e < E) {
            unsigned d = (unsigned)dst[e];
            unsigned s = (unsigned)src[e];
            unsigned p = atomicAdd(&offs[d >> 7], 1u);
            staged[(size_t)e0 + p] = (s << 7) | (d & 127u);
        }
    }
}

// ---------------- CSR pass 2a: per-bucket totals (multi-block, coalesced) ---

__global__ void colsum_kernel(const unsigned* __restrict__ gOffs, int nblk, int nbkt,
                              unsigned* __restrict__ bktCnt) {
    int b = blockIdx.x * 256 + threadIdx.x;
    if (b >= nbkt) return;
    unsigned s = 0;
    for (int blk = 0; blk < nblk; ++blk) {
        const unsigned* row = gOffs + (size_t)blk * (nbkt + 1);
        s += row[b + 1] - row[b];
    }
    bktCnt[b] = s;
}

// ---------------- CSR pass 2b: exclusive scan of bucket totals --------------

__global__ __launch_bounds__(1024) void scan_base(
    const unsigned* __restrict__ bktCnt, int nbkt, unsigned* __restrict__ bktBase)
{
    __shared__ unsigned lds[1024];
    int t = threadIdx.x;
    unsigned v = (t < nbkt) ? bktCnt[t] : 0u;
    lds[t] = v;
    __syncthreads();
    for (int off = 1; off < 1024; off <<= 1) {
        unsigned u = (t >= off) ? lds[t - off] : 0u;
        __syncthreads();
        lds[t] += u;
        __syncthreads();
    }
    if (t <= nbkt) bktBase[t] = lds[t] - v;
}

// ---------------- CSR pass 3: per-bucket node sort -> ssrc + rp -------------

__global__ __launch_bounds__(256) void bucket_gather(
    const unsigned* __restrict__ gOffs, const unsigned* __restrict__ staged,
    const unsigned* __restrict__ bktBase, int nblk, int nbkt, int Nn, int E,
    int* __restrict__ ssrc, int* __restrict__ rp)
{
    __shared__ unsigned segS[256];
    __shared__ unsigned segBase[257];
    __shared__ unsigned tsum[256];
    __shared__ unsigned nodeCnt[128];
    __shared__ unsigned cursor[128];
    __shared__ unsigned ents[GCAP];
    const int tid = threadIdx.x;
    const int bkt = blockIdx.x;
    const int stride = nbkt + 1;

    unsigned len = 0;
    if (tid < nblk) {
        unsigned s = gOffs[(size_t)tid * stride + bkt];
        unsigned e = gOffs[(size_t)tid * stride + bkt + 1];
        segS[tid] = s;
        len = e - s;
    }
    tsum[tid] = len;
    __syncthreads();
    for (int off = 1; off < 256; off <<= 1) {
        unsigned u = (tid >= off) ? tsum[tid - off] : 0u;
        __syncthreads();
        tsum[tid] += u;
        __syncthreads();
    }
    segBase[tid] = tsum[tid] - len;
    if (tid == 255) segBase[256] = tsum[255];
    if (tid < 128) nodeCnt[tid] = 0u;
    __syncthreads();

    const unsigned total = segBase[nblk];
    const bool cached = (total <= (unsigned)GCAP);

    // pass A: per-node counts (+ cache entries)
    for (unsigned p = tid; p < total; p += 256) {
        int lo = 0, hi = nblk;
        while (hi - lo > 1) {
            int mid = (lo + hi) >> 1;
            if (segBase[mid] <= p) lo = mid; else hi = mid;
        }
        unsigned ent = staged[(size_t)lo * EPB + segS[lo] + (p - segBase[lo])];
        if (cached) ents[p] = ent;
        atomicAdd(&nodeCnt[ent & 127u], 1u);
    }
    __syncthreads();

    unsigned nc = (tid < 128) ? nodeCnt[tid] : 0u;
    tsum[tid] = nc;
    __syncthreads();
    for (int off = 1; off < 128; off <<= 1) {
        unsigned u = (tid >= off) ? tsum[tid - off] : 0u;
        __syncthreads();
        tsum[tid] += u;
        __syncthreads();
    }
    if (tid < 128) {
        unsigned off0 = tsum[tid] - nc;
        cursor[tid] = off0;
        int node = bkt * 128 + tid;
        if (node < Nn) rp[node] = (int)(bktBase[bkt] + off0);
    }
    if (bkt == 0 && tid == 0) rp[Nn] = E;
    __syncthreads();

    // pass B: place entries
    const unsigned gbase = bktBase[bkt];
    for (unsigned p = tid; p < total; p += 256) {
        unsigned ent;
        if (cached) {
            ent = ents[p];
        } else {
            int lo = 0, hi = nblk;
            while (hi - lo > 1) {
                int mid = (lo + hi) >> 1;
                if (segBase[mid] <= p) lo = mid; else hi = mid;
            }
            ent = staged[(size_t)lo * EPB + segS[lo] + (p - segBase[lo])];
        }
        unsigned pos = atomicAdd(&cursor[ent & 127u], 1u);
        ssrc[gbase + pos] = (int)(ent >> 7);
    }
}

// ---------------- prep: x->bf16 + all weights/biases (one kernel) ----------

__device__ __forceinline__ void wtr(const float* W, int K, int Nout, u16* Wt,
                                    int rowOff, int idx) {
    int k = idx / Nout, n = idx - k * Nout;
    Wt[(size_t)(n + rowOff) * K + k] = f2b(W[idx]);
}

__global__ void prep_all(
    const float* __restrict__ x, u16* __restrict__ xb, long xchunks,
    const float* __restrict__ Wl1, const float* __restrict__ Wr1,
    const float* __restrict__ Wl2, const float* __restrict__ Wr2,
    const float* __restrict__ Wl3, const float* __restrict__ Wr3,
    const float* __restrict__ Wl4, const float* __restrict__ Wr4,
    const float* __restrict__ b3, const float* __restrict__ b4,
    u16* __restrict__ W1lt, u16* __restrict__ W1rt,
    u16* __restrict__ W2lt, u16* __restrict__ W2rt,
    u16* __restrict__ W3t,  u16* __restrict__ W4t,
    float* __restrict__ b3c, float* __restrict__ b4c)
{
    long gidx = (long)blockIdx.x * 256 + threadIdx.x;
    if (gidx < xchunks) {                       // x -> bf16, 8 elems/thread
        long i = gidx * 8;
        float4 a = *(const float4*)(x + i);
        float4 b = *(const float4*)(x + i + 4);
        u16x8 v;
        v[0] = f2b(a.x); v[1] = f2b(a.y); v[2] = f2b(a.z); v[3] = f2b(a.w);
        v[4] = f2b(b.x); v[5] = f2b(b.y); v[6] = f2b(b.z); v[7] = f2b(b.w);
        *(u16x8*)(xb + i) = v;
        return;
    }
    int idx = (int)(gidx - xchunks);
    if (idx < 32768) { wtr(Wl1, 128, 256, W1lt, 0, idx); return; }
    idx -= 32768;
    if (idx < 32768) { wtr(Wr1, 128, 256, W1rt, 0, idx); return; }
    idx -= 32768;
    if (idx < 65536) { wtr(Wl2, 256, 256, W2lt, 0, idx); return; }
    idx -= 65536;
    if (idx < 65536) { wtr(Wr2, 256, 256, W2rt, 0, idx); return; }
    idx -= 65536;
    if (idx < 16384) { wtr(Wl3, 256, 64, W3t, 0, idx); return; }
    idx -= 16384;
    if (idx < 16384) { wtr(Wr3, 256, 64, W3t, 64, idx); return; }
    idx -= 16384;
    if (idx < 4096)  { wtr(Wl4, 64, 64, W4t, 0, idx); return; }
    idx -= 4096;
    if (idx < 4096)  { wtr(Wr4, 64, 64, W4t, 64, idx); return; }
    idx -= 4096;
    if (idx < 128)   { b3c[idx] = (idx < 64) ? 0.f : b3[idx - 64]; return; }
    idx -= 128;
    if (idx < 128)   { b4c[idx] = (idx < 64) ? 0.f : b4[idx - 64]; return; }
}

// ---------------- mean aggregation: 8-deep pipelined gather -----------------

template <int LPN, bool ADD, bool RELU, bool LSM>
__global__ __launch_bounds__(256) void agg_kernel(
    const u16* __restrict__ feat, int ldF, int offF,
    const u16* __restrict__ addB, int ldA, int offA,
    void* __restrict__ outp, int ldO,
    const int* __restrict__ rp, const int* __restrict__ ssrc, int Nn)
{
    constexpr int NPW = 64 / LPN;
    int lane = threadIdx.x & 63;
    int wid  = threadIdx.x >> 6;
    int sub  = lane / LPN;
    int sl   = lane % LPN;
    int n = (blockIdx.x * 4 + wid) * NPW + sub;
    if (n >= Nn) return;

    int s = rp[n], e = rp[n + 1];
    float acc[8] = {0.f, 0.f, 0.f, 0.f, 0.f, 0.f, 0.f, 0.f};
    const u16* fbase = feat + (size_t)offF + (size_t)sl * 8;

    // 8 edges per iteration: 8 independent gathers in flight before any use
    for (int k = s; k < e; k += 8) {
        int last = e - 1;
        int sc[8];
#pragma unroll
        for (int i = 0; i < 8; ++i) {
            int t = k + i;
            sc[i] = ssrc[t <= last ? t : last];
        }
        u16x8 v[8];
#pragma unroll
        for (int i = 0; i < 8; ++i)
            v[i] = *(const u16x8*)(fbase + (size_t)sc[i] * ldF);
#pragma unroll
        for (int i = 0; i < 8; ++i) {
            if (k + i < e) {
#pragma unroll
                for (int j = 0; j < 8; ++j) acc[j] += b2f(v[i][j]);
            }
        }
    }

    int cnt = e - s;
    float inv = 1.0f / (float)(cnt > 0 ? cnt : 1);
#pragma unroll
    for (int j = 0; j < 8; ++j) acc[j] *= inv;

    if constexpr (ADD) {
        u16x8 v = *(const u16x8*)(addB + (size_t)n * ldA + offA + (size_t)sl * 8);
#pragma unroll
        for (int j = 0; j < 8; ++j) acc[j] += b2f(v[j]);
    }
    if constexpr (RELU) {
#pragma unroll
        for (int j = 0; j < 8; ++j) acc[j] = fmaxf(acc[j], 0.f);
    }

    if constexpr (LSM) {
        float m = acc[0];
#pragma unroll
        for (int j = 1; j < 8; ++j) m = fmaxf(m, acc[j]);
#pragma unroll
        for (int off = 1; off < 8; off <<= 1) m = fmaxf(m, __shfl_xor(m, off));
        float ss = 0.f;
#pragma unroll
        for (int j = 0; j < 8; ++j) ss += expf(acc[j] - m);
#pragma unroll
        for (int off = 1; off < 8; off <<= 1) ss += __shfl_xor(ss, off);
        float lse = m + logf(ss);
        float* o = (float*)outp + (size_t)n * ldO + (size_t)sl * 8;
        *(float4*)o = make_float4(acc[0] - lse, acc[1] - lse, acc[2] - lse, acc[3] - lse);
        *(float4*)(o + 4) = make_float4(acc[4] - lse, acc[5] - lse, acc[6] - lse, acc[7] - lse);
    } else {
        u16x8 v;
#pragma unroll
        for (int j = 0; j < 8; ++j) v[j] = f2b(acc[j]);
        *(u16x8*)((u16*)outp + (size_t)n * ldO + (size_t)sl * 8) = v;
    }
}

// ---------------- bf16 MFMA GEMM: BM=256 BN=128 BK=64, 512 thr --------------
// DUAL grids are 1-D with an XCD-aware remap: within each 16-block group,
// rowblk = group*8 + (bid&7), colblk = (bid>>3)&1 -> the two col-block twins
// sharing A-rows are 8 linear ids apart (same XCD under bid%8 round-robin)
// and temporally adjacent -> twin's A reads hit that XCD's L2.

template <bool DUAL, bool RELU>
__global__ __launch_bounds__(512, 4) void gemm_mfma(
    const u16* __restrict__ A1, const u16* __restrict__ Wt1, int K1,
    const u16* __restrict__ A2, const u16* __restrict__ Wt2, int K2,
    const float* __restrict__ bias,
    u16* __restrict__ outp, int ldOut, int M, int gxRow)
{
    __shared__ u16 sA[256][72];   // [row][k], pad 64->72 (2-way bank alias = free)
    __shared__ u16 sW[128][72];   // [outcol][k]

    int rowblk, colblk;
    if constexpr (DUAL) {
        int bid = blockIdx.x;
        rowblk = (bid >> 4) * 8 + (bid & 7);
        colblk = (bid >> 3) & 1;
        if (rowblk >= gxRow) return;           // wave-uniform early exit
    } else {
        rowblk = blockIdx.x;
        colblk = 0;
    }
    const int row0 = rowblk * 256;
    const int nB   = colblk * 128;

    const int tid = threadIdx.x;
    const int lane = tid & 63, wid = tid >> 6;
    const int wr = wid >> 1, wc = wid & 1;          // 4x2 wave grid
    const int r16 = lane & 15, khalf = lane >> 4;   // khalf 0..3
    f32x4 acc[4][4] = {};

#pragma unroll 1
    for (int s = 0; s < (DUAL ? 2 : 1); ++s) {
        const u16* A  = (s == 0) ? A1 : A2;
        const u16* Wt = (s == 0) ? Wt1 : Wt2;
        const int  K  = (s == 0) ? K1 : K2;
        for (int k0 = 0; k0 < K; k0 += 64) {
#pragma unroll
            for (int it = 0; it < 4; ++it) {
                int idx = it * 512 + tid;
                int r = idx >> 3, kq = (idx & 7) * 8;
                int grow = row0 + r;
                s16x8 v = {};
                if (grow < M) v = *(const s16x8*)(A + (size_t)grow * K + k0 + kq);
                *(s16x8*)&sA[r][kq] = v;
            }
#pragma unroll
            for (int it = 0; it < 2; ++it) {
                int idx = it * 512 + tid;
                int r = idx >> 3, kq = (idx & 7) * 8;
                s16x8 v = *(const s16x8*)(Wt + (size_t)(nB + r) * K + k0 + kq);
                *(s16x8*)&sW[r][kq] = v;
            }
            __syncthreads();

#pragma unroll
            for (int ks = 0; ks < 2; ++ks) {
                const int kb = ks * 32 + khalf * 8;
                s16x8 af[4], bfr[4];
#pragma unroll
                for (int m = 0; m < 4; ++m)
                    af[m] = *(const s16x8*)&sA[wr * 64 + m * 16 + r16][kb];
#pragma unroll
                for (int nn = 0; nn < 4; ++nn)
                    bfr[nn] = *(const s16x8*)&sW[wc * 64 + nn * 16 + r16][kb];
#pragma unroll
                for (int m = 0; m < 4; ++m)
#pragma unroll
                    for (int nn = 0; nn < 4; ++nn)
                        acc[m][nn] = __builtin_amdgcn_mfma_f32_16x16x32_bf16(
                            af[m], bfr[nn], acc[m][nn], 0, 0, 0);
            }
            __syncthreads();
        }
    }

    // epilogue: C/D layout col=lane&15, row=(lane>>4)*4+reg  [m89]
    float bv[4];
#pragma unroll
    for (int nn = 0; nn < 4; ++nn)
        bv[nn] = bias ? bias[nB + wc * 64 + nn * 16 + r16] : 0.f;
#pragma unroll
    for (int m = 0; m < 4; ++m) {
#pragma unroll
        for (int r = 0; r < 4; ++r) {
            int grow = row0 + wr * 64 + m * 16 + khalf * 4 + r;
            if (grow < M) {
#pragma unroll
                for (int nn = 0; nn < 4; ++nn) {
                    float v = acc[m][nn][r] + bv[nn];
                    if constexpr (RELU) v = fmaxf(v, 0.f);
                    outp[(size_t)grow * ldOut + nB + wc * 64 + nn * 16 + r16] = f2b(v);
                }
            }
        }
    }
}

// ---------------- launch ----------------

extern "C" void kernel_launch(void* const* d_in, const int* in_sizes, int n_in,
                              void* d_out, int out_size, void* d_ws, size_t ws_size,
                              hipStream_t stream)
{
    const float* x   = (const float*)d_in[0];
    const int*   ei  = (const int*)d_in[1];
    const float* Wl1 = (const float*)d_in[2];
    const float* Wr1 = (const float*)d_in[3];
    const float* b1  = (const float*)d_in[4];
    const float* Wl2 = (const float*)d_in[5];
    const float* Wr2 = (const float*)d_in[6];
    const float* b2  = (const float*)d_in[7];
    const float* Wl3 = (const float*)d_in[8];
    const float* Wr3 = (const float*)d_in[9];
    const float* b3  = (const float*)d_in[10];
    const float* Wl4 = (const float*)d_in[11];
    const float* Wr4 = (const float*)d_in[12];
    const float* b4  = (const float*)d_in[13];
    float* outp = (float*)d_out;

    const int N = in_sizes[0] / 128;
    const int E = in_sizes[1] / 2;
    const int* src = ei;
    const int* dst = ei + E;

    const int nbkt = (N + 127) >> 7;          // 128-node buckets
    const int nblk = (E + EPB - 1) / EPB;     // pass-1 blocks (must be <=256)

    char* w = (char*)d_ws;
    auto alloc = [&](size_t bytes) -> char* {
        char* p = w;
        w += (bytes + 255) & ~(size_t)255;
        return p;
    };
    int* ssrc = (int*)alloc((size_t)E * 4);
    int* rp   = (int*)alloc((size_t)(N + 1) * 4);
    unsigned* bktCnt  = (unsigned*)alloc((size_t)nbkt * 4);
    unsigned* bktBase = (unsigned*)alloc((size_t)(nbkt + 1) * 4);
    u16* mean1 = (u16*)alloc((size_t)N * 128 * 2);   // reused as t3r3 [N,128]
    u16* h1    = (u16*)alloc((size_t)N * 256 * 2);   // reused: h3 [N,64] + t4r4 [N,128]
    u16* agg2  = (u16*)alloc((size_t)N * 256 * 2);
    u16* h2s   = (u16*)alloc((size_t)N * 256 * 2);   // h2; start doubles as xb AND
                                                     // (earlier) staged+gOffs scratch
    u16* W1lt = (u16*)alloc((size_t)256 * 128 * 2);
    u16* W1rt = (u16*)alloc((size_t)256 * 128 * 2);
    u16* W2lt = (u16*)alloc((size_t)256 * 256 * 2);
    u16* W2rt = (u16*)alloc((size_t)256 * 256 * 2);
    u16* W3t  = (u16*)alloc((size_t)128 * 256 * 2);
    u16* W4t  = (u16*)alloc((size_t)128 * 64 * 2);
    float* b3c = (float*)alloc(128 * 4);
    float* b4c = (float*)alloc(128 * 4);

    // staged + gOffs overlay the h2s slab; dead before prep_all writes xb.
    unsigned* staged = (unsigned*)h2s;
    unsigned* gOffs  = staged + (size_t)nblk * EPB;

    u16* xb   = h2s;                       // [N,128]; written after CSR done
    u16* h2   = h2s;                       // [N,256]
    u16* t3r3 = mean1;                     // [N,128]
    u16* h3   = h1;                        // [N,64]
    u16* t4r4 = h1 + (size_t)N * 64;       // [N,128]

    dim3 blk(256);
    dim3 blkG(512);
    const int gx = (N + 255) / 256;              // GEMM row-blocks (BM=256)
    const int gDual = ((gx + 7) / 8) * 16;       // XCD-paired 1-D grid for dual GEMMs

    // ---- CSR build: atomic-free two-level sort ----
    bucket_pass1<<<nblk, blk, 0, stream>>>(src, dst, E, gOffs, staged, nbkt);
    colsum_kernel<<<(nbkt + 255) / 256, blk, 0, stream>>>(gOffs, nblk, nbkt, bktCnt);
    scan_base<<<1, 1024, 0, stream>>>(bktCnt, nbkt, bktBase);
    bucket_gather<<<nbkt, blk, 0, stream>>>(gOffs, staged, bktBase, nblk, nbkt, N, E,
                                            ssrc, rp);

    // ---- prep (x conversion overwrites staged region — CSR reads done) ----
    long xchunks = (long)N * 128 / 8;
    long ptot = xchunks + 237824;
    prep_all<<<(int)((ptot + 255) / 256), blk, 0, stream>>>(
        x, xb, xchunks,
        Wl1, Wr1, Wl2, Wr2, Wl3, Wr3, Wl4, Wr4, b3, b4,
        W1lt, W1rt, W2lt, W2rt, W3t, W4t, b3c, b4c);

    // ---- layer 1: h1 = relu(mean(xb)@Wl1 + xb@Wr1 + b1) ----
    agg_kernel<16, false, false, false><<<(N + 15) / 16, blk, 0, stream>>>(
        xb, 128, 0, nullptr, 0, 0, mean1, 128, rp, ssrc, N);
    gemm_mfma<true, true><<<gDual, blkG, 0, stream>>>(
        mean1, W1lt, 128, xb, W1rt, 128, b1, h1, 256, N, gx);

    // ---- layer 2: h2 = relu(mean(h1)@Wl2 + h1@Wr2 + b2) ----
    agg_kernel<32, false, false, false><<<(N + 7) / 8, blk, 0, stream>>>(
        h1, 256, 0, nullptr, 0, 0, agg2, 256, rp, ssrc, N);
    gemm_mfma<true, true><<<gDual, blkG, 0, stream>>>(
        agg2, W2lt, 256, h1, W2rt, 256, b2, h2, 256, N, gx);

    // ---- layer 3 (transform-first): [t3|r3] = h2@[Wl3|Wr3] + [0|b3] ----
    gemm_mfma<false, false><<<gx, blkG, 0, stream>>>(
        h2, W3t, 256, nullptr, nullptr, 0, b3c, t3r3, 128, N, gx);
    // h3 = relu(mean(t3) + r3)
    agg_kernel<8, true, true, false><<<(N + 31) / 32, blk, 0, stream>>>(
        t3r3, 128, 0, t3r3, 128, 64, h3, 64, rp, ssrc, N);

    // ---- layer 4 (transform-first): [t4|r4] = h3@[Wl4|Wr4] + [0|b4] ----
    gemm_mfma<false, false><<<gx, blkG, 0, stream>>>(
        h3, W4t, 64, nullptr, nullptr, 0, b4c, t4r4, 128, N, gx);
    // out = log_softmax(mean(t4) + r4)
    agg_kernel<8, true, false, true><<<(N + 31) / 32, blk, 0, stream>>>(
        t4r4, 128, 0, t4r4, 128, 64, outp, 64, rp, ssrc, N);
}